// Round 6
// baseline (1122.785 us; speedup 1.0000x reference)
//
#include <hip/hip_runtime.h>

typedef unsigned short u16;
typedef short bf16x8 __attribute__((ext_vector_type(8)));
typedef float f32x16 __attribute__((ext_vector_type(16)));
typedef unsigned short u16x4v __attribute__((ext_vector_type(4)));
typedef unsigned short u16x8v __attribute__((ext_vector_type(8)));

#define LN_EPS 1e-5f

__device__ __forceinline__ u16 f2bf(float v) {
    unsigned x = __float_as_uint(v);
    x += 0x7fffu + ((x >> 16) & 1u);        // RNE to bf16
    return (u16)(x >> 16);
}
__device__ __forceinline__ float bf2f(u16 u) {
    return __uint_as_float(((unsigned)u) << 16);
}

// ---------------------------------------------------------------------------
// fp32 [R][DIN] row-major -> hi/lo bf16 planes, MFMA-staging layout
// [DIN/8][R][8]. WEIGHTS only (tiny). grid = (R/16, 4), block = 256.
// ---------------------------------------------------------------------------
__global__ __launch_bounds__(256)
void swizzle_split(const float* __restrict__ src, u16* __restrict__ hi,
                   u16* __restrict__ lo, int R, int DIN)
{
    __shared__ __align__(16) u16 SH[2][24][17][8];   // [plane][kc][row(pad)][8]
    const int tid  = threadIdx.x;
    const int row0 = blockIdx.x * 16;
    const int QK   = DIN / 16;
    const int kq0  = QK * blockIdx.y;
    const int NKC  = DIN / 32;

    const int slots = 16 * QK;
    for (int s = tid; s < slots; s += 256) {
        int row = s / QK, kq = s % QK;
        float4 v = *(const float4*)(src + (long)(row0 + row) * DIN + (long)(kq0 + kq) * 4);
        int kc = kq >> 1, jh = (kq & 1) * 4;
        float vv[4] = {v.x, v.y, v.z, v.w};
        u16x4v h, l;
#pragma unroll
        for (int j = 0; j < 4; ++j) {
            u16 hb = f2bf(vv[j]);
            h[j] = hb;
            l[j] = f2bf(vv[j] - bf2f(hb));
        }
        *(u16x4v*)(&SH[0][kc][row][jh]) = h;
        *(u16x4v*)(&SH[1][kc][row][jh]) = l;
    }
    __syncthreads();
    const int chunks = NKC * 16;
    for (int s = tid; s < chunks; s += 256) {
        int row = s & 15, kc = s >> 4;
        long o = ((long)(kq0 / 2 + kc) * R + row0 + row) * 8;
        *(u16x8v*)(hi + o) = *(const u16x8v*)(&SH[0][kc][row][0]);
        *(u16x8v*)(lo + o) = *(const u16x8v*)(&SH[1][kc][row][0]);
    }
}

// ---------------------------------------------------------------------------
// Shared epilogue: bias + LayerNorm + affine + relu, store (optionally
// re-split to swizzled hi/lo bf16 for the next layer).
// C/D layout: col=lane&31, row=(reg&3)+8*(reg>>2)+4*(lane>>5)  [m74/m101].
// ---------------------------------------------------------------------------
template<int DOUT, bool OUT_SPLIT, int NT>
__device__ __forceinline__ void ln_epilogue(
    f32x16 (&acc)[2][NT], float (&lnp)[4][64][2],
    const float* __restrict__ bias, const float* __restrict__ gam,
    const float* __restrict__ bet,
    u16* __restrict__ Yh, u16* __restrict__ Yl, float* __restrict__ Yf,
    long row0, int NR, int wv, int l31, int hh)
{
    float gg[NT], bb[NT], bev[NT];
#pragma unroll
    for (int u = 0; u < NT; ++u) {
        int c = wv * (DOUT / 4) + u * 32 + l31;
        bb[u] = bias[c]; gg[u] = gam[c]; bev[u] = bet[c];
    }
#pragma unroll
    for (int t = 0; t < 2; ++t)
#pragma unroll
        for (int r = 0; r < 16; ++r) {
            float s1 = 0.f, s2 = 0.f;
#pragma unroll
            for (int u = 0; u < NT; ++u) {
                float v = acc[t][u][r] + bb[u];
                acc[t][u][r] = v;
                s1 += v; s2 += v * v;
            }
#pragma unroll
            for (int off = 1; off < 32; off <<= 1) {
                s1 += __shfl_xor(s1, off, 64);
                s2 += __shfl_xor(s2, off, 64);
            }
            int row = t * 32 + (r & 3) + 8 * (r >> 2) + 4 * hh;
            if (l31 == r) { lnp[wv][row][0] = s1; lnp[wv][row][1] = s2; }
        }
    __syncthreads();
#pragma unroll
    for (int t = 0; t < 2; ++t)
#pragma unroll
        for (int r = 0; r < 16; ++r) {
            int row = t * 32 + (r & 3) + 8 * (r >> 2) + 4 * hh;
            float s1 = lnp[0][row][0] + lnp[1][row][0] + lnp[2][row][0] + lnp[3][row][0];
            float s2 = lnp[0][row][1] + lnp[1][row][1] + lnp[2][row][1] + lnp[3][row][1];
            float mean = s1 * (1.f / DOUT);
            float inv  = rsqrtf(s2 * (1.f / DOUT) - mean * mean + LN_EPS);
            long gr = row0 + row;
#pragma unroll
            for (int u = 0; u < NT; ++u) {
                int c = wv * (DOUT / 4) + u * 32 + l31;
                float v = (acc[t][u][r] - mean) * inv * gg[u] + bev[u];
                v = fmaxf(v, 0.f);
                if (OUT_SPLIT) {
                    u16 hv = f2bf(v);
                    long o = ((long)(c >> 3) * NR + gr) * 8 + (c & 7);
                    Yh[o] = hv;
                    Yl[o] = f2bf(v - bf2f(hv));
                } else {
                    Yf[gr * DOUT + c] = v;
                }
            }
        }
}

// ---------------------------------------------------------------------------
// Layers 2/3: BARRIER-FREE streaming K-loop. A and W frags load directly
// global->VGPR from swizzled [kc][row][8] layouts (coalesced 512B segments);
// cross-wave A redundancy is absorbed by L1 (same CU, same addresses).
// No __syncthreads until the epilogue -> no vmcnt(0) drain; compiler emits
// fine-grained vmcnt waits and the 2 waves/SIMD interleave MFMA issue.
// ---------------------------------------------------------------------------
template<int DOUT, bool OUT_SPLIT>
__global__ __launch_bounds__(256, 2)
void mfma_stream(const u16* __restrict__ Ah, const u16* __restrict__ Al,
                 const u16* __restrict__ Wh, const u16* __restrict__ Wl,
                 const float* __restrict__ bias, const float* __restrict__ gam,
                 const float* __restrict__ bet,
                 u16* __restrict__ Yh, u16* __restrict__ Yl,
                 float* __restrict__ Yf, int DIN, int NR)
{
    constexpr int NT = DOUT / 128;
    __shared__ float lnp[4][64][2];

    const int tid  = threadIdx.x;
    const int lane = tid & 63, wv = tid >> 6;
    const int l31  = lane & 31, hh = lane >> 5;
    const long row0 = (long)blockIdx.x * 64;

    const u16* pA[2][2];
#pragma unroll
    for (int t = 0; t < 2; ++t) {
        long o = ((long)hh * NR + row0 + t * 32 + l31) * 8;
        pA[t][0] = Ah + o;
        pA[t][1] = Al + o;
    }
    const u16* pW[NT][2];
#pragma unroll
    for (int u = 0; u < NT; ++u) {
        long o = ((long)hh * DOUT + wv * (DOUT / 4) + u * 32 + l31) * 8;
        pW[u][0] = Wh + o;
        pW[u][1] = Wl + o;
    }
    const long sA = (long)2 * NR * 8;
    const long sW = (long)2 * DOUT * 8;

    f32x16 acc[2][NT];
#pragma unroll
    for (int t = 0; t < 2; ++t)
#pragma unroll
        for (int u = 0; u < NT; ++u)
#pragma unroll
            for (int e = 0; e < 16; ++e) acc[t][u][e] = 0.f;

    for (int ks = 0; ks < DIN / 16; ++ks) {
        bf16x8 af[2][2], wf[NT][2];
#pragma unroll
        for (int t = 0; t < 2; ++t)
#pragma unroll
            for (int p = 0; p < 2; ++p) {
                af[t][p] = *(const bf16x8*)pA[t][p];
                pA[t][p] += sA;
            }
#pragma unroll
        for (int u = 0; u < NT; ++u)
#pragma unroll
            for (int p = 0; p < 2; ++p) {
                wf[u][p] = *(const bf16x8*)pW[u][p];
                pW[u][p] += sW;
            }
#pragma unroll
        for (int t = 0; t < 2; ++t)
#pragma unroll
            for (int u = 0; u < NT; ++u) {
                acc[t][u] = __builtin_amdgcn_mfma_f32_32x32x16_bf16(af[t][0], wf[u][0], acc[t][u], 0, 0, 0);
                acc[t][u] = __builtin_amdgcn_mfma_f32_32x32x16_bf16(af[t][0], wf[u][1], acc[t][u], 0, 0, 0);
                acc[t][u] = __builtin_amdgcn_mfma_f32_32x32x16_bf16(af[t][1], wf[u][0], acc[t][u], 0, 0, 0);
            }
    }

    ln_epilogue<DOUT, OUT_SPLIT, NT>(acc, lnp, bias, gam, bet, Yh, Yl, Yf,
                                     row0, NR, wv, l31, hh);
}

// ---------------------------------------------------------------------------
// Layer 1: BARRIER-FREE, fp32 X input. A-frags load raw fp32 directly
// (lanes l and l+32 share one 64B line: 32 full lines/instr) and split to
// hi/lo bf16 in-register (VALU overlaps the MFMA pipe). W as above.
// ---------------------------------------------------------------------------
template<int DOUT>
__global__ __launch_bounds__(256, 2)
void mfma_stream1(const float* __restrict__ X,
                  const u16* __restrict__ Wh, const u16* __restrict__ Wl,
                  const float* __restrict__ bias, const float* __restrict__ gam,
                  const float* __restrict__ bet,
                  u16* __restrict__ Yh, u16* __restrict__ Yl,
                  int DIN, int NR, long rbase)
{
    constexpr int NT = DOUT / 128;
    __shared__ float lnp[4][64][2];

    const int tid  = threadIdx.x;
    const int lane = tid & 63, wv = tid >> 6;
    const int l31  = lane & 31, hh = lane >> 5;
    const long lrow0 = (long)blockIdx.x * 64;
    const long row0  = rbase + lrow0;

    const float* pX[2];
#pragma unroll
    for (int t = 0; t < 2; ++t)
        pX[t] = X + (lrow0 + t * 32 + l31) * DIN + hh * 8;

    const u16* pW[NT][2];
#pragma unroll
    for (int u = 0; u < NT; ++u) {
        long o = ((long)hh * DOUT + wv * (DOUT / 4) + u * 32 + l31) * 8;
        pW[u][0] = Wh + o;
        pW[u][1] = Wl + o;
    }
    const long sW = (long)2 * DOUT * 8;

    f32x16 acc[2][NT];
#pragma unroll
    for (int t = 0; t < 2; ++t)
#pragma unroll
        for (int u = 0; u < NT; ++u)
#pragma unroll
            for (int e = 0; e < 16; ++e) acc[t][u][e] = 0.f;

    for (int ks = 0; ks < DIN / 16; ++ks) {
        bf16x8 af[2][2], wf[NT][2];
#pragma unroll
        for (int t = 0; t < 2; ++t) {
            float4 v0 = *(const float4*)pX[t];
            float4 v1 = *(const float4*)(pX[t] + 4);
            pX[t] += 16;
            float f[8] = {v0.x, v0.y, v0.z, v0.w, v1.x, v1.y, v1.z, v1.w};
            u16x8v h, l;
#pragma unroll
            for (int j = 0; j < 8; ++j) {
                u16 hb = f2bf(f[j]);
                h[j] = hb;
                l[j] = f2bf(f[j] - bf2f(hb));
            }
            af[t][0] = *(bf16x8*)&h;
            af[t][1] = *(bf16x8*)&l;
        }
#pragma unroll
        for (int u = 0; u < NT; ++u)
#pragma unroll
            for (int p = 0; p < 2; ++p) {
                wf[u][p] = *(const bf16x8*)pW[u][p];
                pW[u][p] += sW;
            }
#pragma unroll
        for (int t = 0; t < 2; ++t)
#pragma unroll
            for (int u = 0; u < NT; ++u) {
                acc[t][u] = __builtin_amdgcn_mfma_f32_32x32x16_bf16(af[t][0], wf[u][0], acc[t][u], 0, 0, 0);
                acc[t][u] = __builtin_amdgcn_mfma_f32_32x32x16_bf16(af[t][0], wf[u][1], acc[t][u], 0, 0, 0);
                acc[t][u] = __builtin_amdgcn_mfma_f32_32x32x16_bf16(af[t][1], wf[u][0], acc[t][u], 0, 0, 0);
            }
    }

    ln_epilogue<DOUT, true, NT>(acc, lnp, bias, gam, bet, Yh, Yl, nullptr,
                                row0, NR, wv, l31, hh);
}

// ---------------------------------------------------------------------------
// Layer 4: Z = H @ W4^T + b4   (128 -> 32, fp32). One thread per row.
// ---------------------------------------------------------------------------
__global__ __launch_bounds__(256)
void layer4_k(const float* __restrict__ H, const float* __restrict__ W4,
              const float* __restrict__ b4, float* __restrict__ Z)
{
    __shared__ float Ws[32 * 128];
    __shared__ float bs[32];
    const int tid = threadIdx.x;
    for (int idx = tid; idx < 4096; idx += 256) Ws[idx] = W4[idx];
    if (tid < 32) bs[tid] = b4[tid];
    __syncthreads();

    long r = (long)blockIdx.x * 256 + tid;
    float acc[32];
#pragma unroll
    for (int c = 0; c < 32; ++c) acc[c] = 0.f;
    for (int k = 0; k < 128; k += 4) {
        float4 x = *(const float4*)(H + r * 128 + k);
#pragma unroll
        for (int c = 0; c < 32; ++c) {
            acc[c] = fmaf(x.x, Ws[c * 128 + k + 0], acc[c]);
            acc[c] = fmaf(x.y, Ws[c * 128 + k + 1], acc[c]);
            acc[c] = fmaf(x.z, Ws[c * 128 + k + 2], acc[c]);
            acc[c] = fmaf(x.w, Ws[c * 128 + k + 3], acc[c]);
        }
    }
#pragma unroll
    for (int c = 0; c < 32; ++c) Z[r * 32 + c] = acc[c] + bs[c];
}

// ---------------------------------------------------------------------------
// Prototypes: one block per class, no atomics.
// ---------------------------------------------------------------------------
__global__ __launch_bounds__(256)
void proto_k(const float* __restrict__ Zs, const int* __restrict__ lab,
             float* __restrict__ P)
{
    const int c = blockIdx.x;
    const int tid = threadIdx.x, lane = tid & 63, wv = tid >> 6;
    float acc[32];
#pragma unroll
    for (int d = 0; d < 32; ++d) acc[d] = 0.f;
    float cnt = 0.f;
    for (int i = tid; i < 32768; i += 256) {
        if (lab[i] == c) {
            cnt += 1.f;
#pragma unroll
            for (int d = 0; d < 32; ++d) acc[d] += Zs[(long)i * 32 + d];
        }
    }
    __shared__ float wsum[4][32];
    __shared__ float wcnt[4];
#pragma unroll
    for (int d = 0; d < 32; ++d) {
        float v = acc[d];
        for (int off = 32; off > 0; off >>= 1) v += __shfl_xor(v, off, 64);
        if (lane == 0) wsum[wv][d] = v;
    }
    {
        float v = cnt;
        for (int off = 32; off > 0; off >>= 1) v += __shfl_xor(v, off, 64);
        if (lane == 0) wcnt[wv] = v;
    }
    __syncthreads();
    if (tid < 32) {
        float s  = wsum[0][tid] + wsum[1][tid] + wsum[2][tid] + wsum[3][tid];
        float cn = wcnt[0] + wcnt[1] + wcnt[2] + wcnt[3];
        P[c * 32 + tid] = s / fmaxf(cn, 1.f);
    }
}

// ---------------------------------------------------------------------------
// -cdist: one thread per query row, protos in LDS.
// ---------------------------------------------------------------------------
__global__ __launch_bounds__(256)
void dist_k(const float* __restrict__ Zq, const float* __restrict__ P,
            float* __restrict__ O)
{
    __shared__ float ps[64 * 32];
    __shared__ float pn[64];
    const int tid = threadIdx.x;
    for (int idx = tid; idx < 2048; idx += 256) ps[idx] = P[idx];
    __syncthreads();
    if (tid < 64) {
        float s = 0.f;
        for (int d = 0; d < 32; ++d) { float v = ps[tid * 32 + d]; s += v * v; }
        pn[tid] = s;
    }
    __syncthreads();

    long q = (long)blockIdx.x * 256 + tid;
    float zr[32];
#pragma unroll
    for (int d = 0; d < 32; d += 4) {
        float4 v = *(const float4*)(Zq + q * 32 + d);
        zr[d] = v.x; zr[d + 1] = v.y; zr[d + 2] = v.z; zr[d + 3] = v.w;
    }
    float zz = 0.f;
#pragma unroll
    for (int d = 0; d < 32; ++d) zz += zr[d] * zr[d];
    for (int p = 0; p < 64; ++p) {
        float dot = 0.f;
#pragma unroll
        for (int d = 0; d < 32; ++d) dot = fmaf(zr[d], ps[p * 32 + d], dot);
        float sq = zz + pn[p] - 2.f * dot;
        O[q * 64 + p] = -sqrtf(fmaxf(sq, 0.f));
    }
}

// ---------------------------------------------------------------------------
// Host side — single pass over all 98304 rows.
// ---------------------------------------------------------------------------
extern "C" void kernel_launch(void* const* d_in, const int* in_sizes, int n_in,
                              void* d_out, int out_size, void* d_ws, size_t ws_size,
                              hipStream_t stream)
{
    const float* supp = (const float*)d_in[0];   // [32768,768]
    const int*   lab  = (const int*)  d_in[1];   // [32768]
    const float* qry  = (const float*)d_in[2];   // [65536,768]
    const float* W1 = (const float*)d_in[3];  const float* b1 = (const float*)d_in[4];
    const float* g1 = (const float*)d_in[5];  const float* be1= (const float*)d_in[6];
    const float* W2 = (const float*)d_in[7];  const float* b2 = (const float*)d_in[8];
    const float* g2 = (const float*)d_in[9];  const float* be2= (const float*)d_in[10];
    const float* W3 = (const float*)d_in[11]; const float* b3 = (const float*)d_in[12];
    const float* g3 = (const float*)d_in[13]; const float* be3= (const float*)d_in[14];
    const float* W4 = (const float*)d_in[15]; const float* b4 = (const float*)d_in[16];
    float* out = (float*)d_out;                  // [65536,64]

    const long NTOT = 98304, NS = 32768, NQ = 65536;
    const int  NR = (int)NTOT;

    char* wsp = (char*)d_ws;
    size_t off = 0;
    auto take = [&](size_t bytes) {
        char* p = wsp + off;
        off += (bytes + 255) & ~(size_t)255;
        return (void*)p;
    };

    float* zAll  = (float*)take((size_t)NTOT * 32 * 4);
    float* proto = (float*)take(2048 * 4);
    u16* W1h = (u16*)take((size_t)512 * 768 * 2);
    u16* W1l = (u16*)take((size_t)512 * 768 * 2);
    u16* W2h = (u16*)take((size_t)512 * 512 * 2);
    u16* W2l = (u16*)take((size_t)512 * 512 * 2);
    u16* W3h = (u16*)take((size_t)128 * 512 * 2);
    u16* W3l = (u16*)take((size_t)128 * 512 * 2);
    u16* h1h = (u16*)take((size_t)NTOT * 512 * 2);
    u16* h1l = (u16*)take((size_t)NTOT * 512 * 2);
    u16* h2h = (u16*)take((size_t)NTOT * 512 * 2);
    u16* h2l = (u16*)take((size_t)NTOT * 512 * 2);
    float* h3 = (float*)take((size_t)NTOT * 128 * 4);

    // split+swizzle weights (tiny)
    swizzle_split<<<dim3(32, 4), dim3(256), 0, stream>>>(W1, W1h, W1l, 512, 768);
    swizzle_split<<<dim3(32, 4), dim3(256), 0, stream>>>(W2, W2h, W2l, 512, 512);
    swizzle_split<<<dim3(8, 4),  dim3(256), 0, stream>>>(W3, W3h, W3l, 128, 512);

    // layer 1: fused fp32->split, barrier-free streaming
    mfma_stream1<512><<<dim3(NS / 64), dim3(256), 0, stream>>>(
        supp, W1h, W1l, b1, g1, be1, h1h, h1l, 768, NR, 0);
    mfma_stream1<512><<<dim3(NQ / 64), dim3(256), 0, stream>>>(
        qry, W1h, W1l, b1, g1, be1, h1h, h1l, 768, NR, NS);

    mfma_stream<512, true><<<dim3(NTOT / 64), dim3(256), 0, stream>>>(
        h1h, h1l, W2h, W2l, b2, g2, be2, h2h, h2l, nullptr, 512, NR);
    mfma_stream<128, false><<<dim3(NTOT / 64), dim3(256), 0, stream>>>(
        h2h, h2l, W3h, W3l, b3, g3, be3, nullptr, nullptr, h3, 512, NR);
    layer4_k<<<dim3(NTOT / 256), dim3(256), 0, stream>>>(h3, W4, b4, zAll);

    proto_k<<<dim3(64),  dim3(256), 0, stream>>>(zAll, lab, proto);
    dist_k<<<dim3(256), dim3(256), 0, stream>>>(zAll + NS * 32, proto, out);
}